// Round 13
// baseline (214.858 us; speedup 1.0000x reference)
//
#include <hip/hip_runtime.h>
#include <hip/hip_bf16.h>

typedef __bf16 bf16;
typedef __bf16 bf16x8 __attribute__((ext_vector_type(8)));
typedef __bf16 bf16x4 __attribute__((ext_vector_type(4)));
typedef float  f32x4  __attribute__((ext_vector_type(4)));

#define GLD_LDS(g, l)                                                        \
  __builtin_amdgcn_global_load_lds(                                          \
      (const __attribute__((address_space(1))) void*)(g),                    \
      (__attribute__((address_space(3))) void*)(l), 16, 0, 0)

#define SB()    __builtin_amdgcn_s_barrier()
#define WVM(n)  asm volatile("s_waitcnt vmcnt(" #n ")" ::: "memory")
#define PRIO1() __builtin_amdgcn_s_setprio(1)
#define PRIO0() __builtin_amdgcn_s_setprio(0)

// ---------------------------------------------------------------------------
// gemm128k: 128x128 tile, BK=64 split in kk-halves (32 k each), 8 waves
// (4Mx2N, wave tile 32x64), LDS 64 KiB => TWO blocks/CU (16 waves/CU).
// Cross-block overlap (per-wave vmcnt, per-block barriers) hides store
// drains, prologue fills, and barrier skew — the measured junction cost of
// the 1-block/CU 256x256 design (FIFO vmcnt: stores poison later load
// gates; with a peer block resident the CU never idles on them).
// Schedule per K-tile (2 barriers, 2 counted gates):
//   [rd kk0: af(2)+bg np0(2)] [stg A.kk0(T+1)] MM(np0)
//   [rd bg np1 kk0(2)]        [stg B.kk0(T+1)] MM(np1)  WVM(2) SB
//   [rd kk1: af+bg np0]       [stg A.kk1(T+1)] MM(np0)
//   [rd bg np1 kk1]           [stg B.kk1(T+1)] MM(np1)  WVM(2) SB
// Every WVM(2) waits only on loads staged exactly 2 phases earlier; leaves
// the 2 newest in flight (T4 counted gates). Prologue: 4 issues + WVM(2).
// Tail (T+1>=NT): skip stages, gates WVM(0).
// Cross-wave safety: each wave's ds_reads complete before its MFMAs issue
// (compiler lgkm waits), MFMAs precede the barrier => at barrier arrival
// all reads of the overwritten region are retired; stages target the other
// buffer parity within a tile. Re-derived both directions.
// LDS: A 2buf x 2kk x 8KB @0 (32K); B same @32768. 64B rows (128 rows x
// 32 cols bf16); swizzle slot = fq ^ (row&3) (row&3 == fr&3 on reads —
// exactly 2 lanes/bank = free per m136); staging source pre-applies the
// same XOR involution, gld_lds dest linear (rule #21 both-sides).
// EPI=0: bf16 C. EPI=1: fp32 C + bias. C = A (MxK rm) * B^T (B NxK rm).
// M,N%128==0, K=1024.
// ---------------------------------------------------------------------------
template <int EPI, int NP>
__global__ __launch_bounds__(512, 4)
void gemm128k(const bf16* __restrict__ A, const bf16* __restrict__ B,
              bf16* __restrict__ Cb, float* __restrict__ Cf,
              const float* __restrict__ bias_p, int M) {
  constexpr int KP = 1024;
  constexpr int NT = KP / 64;           // 16 K-tiles
  extern __shared__ char lds[];
  const int tid  = threadIdx.x;
  const int lane = tid & 63, wave = tid >> 6;
  const int wm = wave >> 1, wn = wave & 1;      // 4 x 2 waves
  const int fr = lane & 15, fq = lane >> 4;
  const int slotb = ((fq ^ (fr & 3)) << 4);     // read-side swizzle (16B slot)

  // ---- block -> output tile ----
  const int nwg = gridDim.x;
  const int bid = blockIdx.x;
  constexpr int gx = NP >> 7;
  const int nTiles = (M >> 7) * gx;
  int tr, tc;
  if (NP == 8192 && nwg == 4096) {
    // 8 sets of 512 co-resident blocks; set = 16x32 tile region (L3);
    // per XCD an 8x8 sub-region (A 2MB + B 2MB ~ L2).
    const int set = bid >> 9, idx = bid & 511;
    const int xcd = idx & 7, pos = idx >> 3;    // pos 0..63
    tr = (set >> 1) * 16 + (xcd >> 2) * 8 + (pos >> 3);
    tc = (set & 1) * 32 + (xcd & 3) * 8 + (pos & 7);
  } else {
    const int swz = (bid & 7) * (nTiles >> 3) + (bid >> 3);
    tr = swz / gx; tc = swz % gx;
  }
  const int row0 = tr << 7, col0 = tc << 7;

  // ---- staging source (pre-swizzled k-chunk; thread t -> LDS byte t*16) --
  // row = t>>2 (0..127), slot = t&3 holds chunk (t&3) ^ ((t>>2)&3)
  const int srow  = tid >> 2;
  const int chunk = (tid & 3) ^ ((tid >> 2) & 3);
  const bf16* Agl = A + (size_t)(row0 + srow) * KP + chunk * 8;
  const bf16* Bgl = B + (size_t)(col0 + srow) * KP + chunk * 8;

  // stage one kk-half of tile t; base_off: A=0, B=32768 (bytes)
#define STG1(gp, base_off, t, kk)                                            \
  GLD_LDS((gp) + (size_t)(t) * 64 + (kk) * 32,                               \
          lds + (base_off) + ((t) & 1) * 16384 + (kk) * 8192 + wave * 1024)

  // ---- LDS read bases ----
  const char* Ab = lds + wm * 2048 + fr * 64 + slotb;          // +p*16K+kk*8K+m*1K
  const char* Bb = lds + 32768 + wn * 4096 + fr * 64 + slotb;  // +p*16K+kk*8K+n*1K

  f32x4  acc[2][4] = {};
  bf16x8 af[2], bg[4];

#define LDA(kk, p)                                                           \
  do {                                                                       \
    _Pragma("unroll") for (int m_ = 0; m_ < 2; ++m_)                         \
      af[m_] = *(const bf16x8*)(Ab + (p) * 16384 + (kk) * 8192 + m_ * 1024); \
  } while (0)

#define LDBH(np, kk, p)                                                      \
  do {                                                                       \
    _Pragma("unroll") for (int n_ = 0; n_ < 2; ++n_)                         \
      bg[(np) * 2 + n_] = *(const bf16x8*)(Bb + (p) * 16384 + (kk) * 8192 +  \
                                           ((np) * 2 + n_) * 1024);          \
  } while (0)

#define MM(np)                                                               \
  do {                                                                       \
    _Pragma("unroll") for (int m_ = 0; m_ < 2; ++m_)                         \
      _Pragma("unroll") for (int n_ = 0; n_ < 2; ++n_)                       \
        acc[m_][(np) * 2 + n_] = __builtin_amdgcn_mfma_f32_16x16x32_bf16(    \
            af[m_], bg[(np) * 2 + n_], acc[m_][(np) * 2 + n_], 0, 0, 0);     \
  } while (0)

  // prologue: T0 kk0 (A,B) then kk1 (A,B); WVM(2) drains kk0, leaves kk1
  STG1(Agl, 0, 0, 0); STG1(Bgl, 32768, 0, 0);
  STG1(Agl, 0, 0, 1); STG1(Bgl, 32768, 0, 1);
  WVM(2); SB();

  for (int T = 0; T < NT; ++T) {
    const int p = T & 1;
    const bool st = (T + 1 < NT);
    // half 1 (kk0 of T); stages kk0 of T+1
    LDA(0, p); LDBH(0, 0, p);
    if (st) STG1(Agl, 0, T + 1, 0);
    PRIO1(); MM(0); PRIO0();
    LDBH(1, 0, p);
    if (st) STG1(Bgl, 32768, T + 1, 0);
    PRIO1(); MM(1); PRIO0();
    if (st) { WVM(2); } else { WVM(0); }
    SB();
    // half 2 (kk1 of T); stages kk1 of T+1
    LDA(1, p); LDBH(0, 1, p);
    if (st) STG1(Agl, 0, T + 1, 1);
    PRIO1(); MM(0); PRIO0();
    LDBH(1, 1, p);
    if (st) STG1(Bgl, 32768, T + 1, 1);
    PRIO1(); MM(1); PRIO0();
    if (st) { WVM(2); } else { WVM(0); }
    SB();
  }

  // epilogue — C/D layout (verified): col = lane&15, row = (lane>>4)*4 + j
  const float bias = (EPI == 1) ? bias_p[0] : 0.0f;
#pragma unroll
  for (int m = 0; m < 2; ++m) {
#pragma unroll
    for (int n = 0; n < 4; ++n) {
      const int r = row0 + wm * 32 + m * 16 + fq * 4;
      const int c = col0 + wn * 64 + n * 16 + fr;
#pragma unroll
      for (int j = 0; j < 4; ++j) {
        if (EPI == 1)
          Cf[(size_t)(r + j) * NP + c] = acc[m][n][j] + bias;
        else
          Cb[(size_t)(r + j) * NP + c] = (bf16)acc[m][n][j];
      }
    }
  }
#undef STG1
#undef LDA
#undef LDBH
#undef MM
}

// fp32 -> bf16 cast, 4 elems/thread
__global__ void cvt_f32_bf16(const float* __restrict__ in, bf16* __restrict__ out,
                             int n4) {
  int i = blockIdx.x * blockDim.x + threadIdx.x;
  if (i >= n4) return;
  const float4 v = ((const float4*)in)[i];
  bf16x4 o;
  o[0] = (bf16)v.x; o[1] = (bf16)v.y; o[2] = (bf16)v.z; o[3] = (bf16)v.w;
  ((bf16x4*)out)[i] = o;
}

// Wt[n][k] = (bf16) W[k][n], 1024x1024
__global__ void transpose_cvt_w(const float* __restrict__ W, bf16* __restrict__ Wt) {
  __shared__ float s[32][33];
  const int tx = threadIdx.x & 31;
  const int ty = threadIdx.x >> 5;
  const int n0 = blockIdx.x * 32;
  const int k0 = blockIdx.y * 32;
#pragma unroll
  for (int p = 0; p < 4; ++p)
    s[ty + p * 8][tx] = W[(size_t)(k0 + ty + p * 8) * 1024 + n0 + tx];
  __syncthreads();
#pragma unroll
  for (int p = 0; p < 4; ++p)
    Wt[(size_t)(n0 + ty + p * 8) * 1024 + k0 + tx] = (bf16)s[tx][ty + p * 8];
}

extern "C" void kernel_launch(void* const* d_in, const int* in_sizes, int n_in,
                              void* d_out, int out_size, void* d_ws, size_t ws_size,
                              hipStream_t stream) {
  const float* X = (const float*)d_in[0];   // (8192, 1024)
  const float* W = (const float*)d_in[1];   // (1024, 1024)
  const float* b = (const float*)d_in[2];   // (1,)
  float* out = (float*)d_out;               // (8192, 8192)

  const int Nn = 8192, D = 1024;
  char* ws = (char*)d_ws;
  bf16* Xb  = (bf16*)(ws);
  bf16* XWb = (bf16*)(ws + (size_t)16 * 1024 * 1024);
  bf16* Wt  = (bf16*)(ws + (size_t)32 * 1024 * 1024);

  cvt_f32_bf16<<<(Nn * D / 4 + 255) / 256, 256, 0, stream>>>(X, Xb, Nn * D / 4);
  transpose_cvt_w<<<dim3(D / 32, D / 32), 256, 0, stream>>>(W, Wt);
  // GEMM1: XW = Xb * Wt^T  (8192x1024) -> bf16; 512 tiles (1 wave of blocks)
  gemm128k<0, 1024><<<512, 512, 65536, stream>>>(Xb, Wt, XWb, nullptr, nullptr,
                                                 Nn);
  // GEMM2: out = XWb * Xb^T + b  (8192x8192) fp32; 4096 tiles, 2 blocks/CU
  gemm128k<1, 8192><<<4096, 512, 65536, stream>>>(XWb, Xb, nullptr, out, b, Nn);
}